// Round 14
// baseline (14530.449 us; speedup 1.0000x reference)
//
#include <hip/hip_runtime.h>
#include <hip/hip_bf16.h>
#include <math.h>

#define MINN 1e-7f
#define BB 64
#define SS 128
#define NCOL 3840

typedef float f4 __attribute__((ext_vector_type(4)));
typedef short bf16x8 __attribute__((ext_vector_type(8)));
typedef float f32x4 __attribute__((ext_vector_type(4)));
typedef _Float16 h2 __attribute__((ext_vector_type(2)));

__device__ __forceinline__ float artanh_c(float x) {
  x = fminf(fmaxf(x, -1.0f + 1e-6f), 1.0f - 1e-6f);
  return atanhf(x);
}
__device__ __forceinline__ float tan_k_(float x, float sq) { return tanhf(sq * x) / sq; }
__device__ __forceinline__ float artan_k_(float x, float sq) { return artanh_c(sq * x) / sq; }

// 2-way fp16 dot with f32 accumulate (v_dot2_f32_f16); fallback keeps correctness.
__device__ __forceinline__ float fdot2u(unsigned wa, unsigned wb, float c) {
  union U { unsigned u; h2 v; };
  U A, B;
  A.u = wa;
  B.u = wb;
#if __has_builtin(__builtin_amdgcn_fdot2)
  return __builtin_amdgcn_fdot2(A.v, B.v, c, false);
#else
  return c + (float)A.v.x * (float)B.v.x + (float)A.v.y * (float)B.v.y;
#endif
}

__device__ __forceinline__ unsigned pk16(float a, float b) {
  union U { h2 v; unsigned u; } X;
  X.v.x = (_Float16)a;
  X.v.y = (_Float16)b;
  return X.u;
}
__device__ __forceinline__ void unpk(unsigned u, float& x, float& y) {
  union U { unsigned u; h2 v; } X;
  X.u = u;
  x = (float)X.v.x;
  y = (float)X.v.y;
}

// Block reduction over 768 threads (12 waves).
template <int N>
__device__ __forceinline__ void redu12(float* v, float* red) {
#pragma unroll
  for (int m = 1; m < 64; m <<= 1)
#pragma unroll
    for (int i = 0; i < N; ++i) v[i] += __shfl_xor(v[i], m, 64);
  int wid = threadIdx.x >> 6, lane = threadIdx.x & 63;
  if (lane == 0)
#pragma unroll
    for (int i = 0; i < N; ++i) red[wid * N + i] = v[i];
  __syncthreads();
#pragma unroll
  for (int i = 0; i < N; ++i) {
    float s = 0.f;
#pragma unroll
    for (int w = 0; w < 12; ++w) s += red[w * N + i];
    v[i] = s;
  }
  __syncthreads();
}

// Combined weights as fp16, k-quad-packed: W4[k4][col] = uint2{h2(k0,k1),h2(k2,k3)}.
// col<768: W_d[col][k]; else m=(col-768)%768, g=(col-768)/768: W_all[m][g*768+k].
__global__ __launch_bounds__(256) void k_build_w4(const float* __restrict__ W_all,
                                                  const float* __restrict__ W_d,
                                                  uint2* __restrict__ W4) {
  int k4 = blockIdx.x;  // 0..191
  for (int col = threadIdx.x; col < NCOL; col += 256) {
    float v[4];
#pragma unroll
    for (int q = 0; q < 4; ++q) {
      int k = 4 * k4 + q;
      if (col < 768) {
        v[q] = W_d[col * 768 + k];
      } else {
        int jm = col - 768;
        int g = jm / 768;
        int m = jm - g * 768;
        v[q] = W_all[m * 3072 + g * 768 + k];
      }
    }
    uint2 w;
    w.x = pk16(v[0], v[1]);
    w.y = pk16(v[2], v[3]);
    W4[(size_t)k4 * NCOL + col] = w;
  }
}

__global__ __launch_bounds__(256) void k_xnorm(const float* __restrict__ X,
                                               float* __restrict__ XN) {
  __shared__ float red[4];
  int r = blockIdx.x;
  float s = 0.f;
#pragma unroll
  for (int p = 0; p < 3; ++p) {
    float v = X[(size_t)r * 768 + threadIdx.x + 256 * p];
    s += v * v;
  }
#pragma unroll
  for (int m = 1; m < 64; m <<= 1) s += __shfl_xor(s, m, 64);
  if ((threadIdx.x & 63) == 0) red[threadIdx.x >> 6] = s;
  __syncthreads();
  if (threadIdx.x == 0) XN[r] = fmaxf(sqrtf(red[0] + red[1] + red[2] + red[3]), MINN);
}

// Split fp32 -> bf16 hi + bf16 lo (residual). Processes 4 elems/thread.
__global__ __launch_bounds__(256) void k_split(const float* __restrict__ src,
                                               __hip_bfloat16* __restrict__ hi,
                                               __hip_bfloat16* __restrict__ lo, int n4) {
  int i = blockIdx.x * 256 + threadIdx.x;
  if (i >= n4) return;
  f4 v = *(const f4*)(src + (size_t)i * 4);
#pragma unroll
  for (int j = 0; j < 4; ++j) {
    float x = (j == 0) ? v.x : (j == 1) ? v.y : (j == 2) ? v.z : v.w;
    __hip_bfloat16 h = __float2bfloat16(x);
    float r = x - __bfloat162float(h);
    hi[(size_t)i * 4 + j] = h;
    lo[(size_t)i * 4 + j] = __float2bfloat16(r);
  }
}

// MFMA U-path GEMM, 2-pass (xh*uh + xl*uh): OUT[i][m] = sum_k X[i][k]*U[m][k].
__global__ __launch_bounds__(256) void k_gemm_xu_mfma(
    const __hip_bfloat16* __restrict__ Xh, const __hip_bfloat16* __restrict__ Xl,
    const __hip_bfloat16* __restrict__ Uh, __hip_bfloat16* __restrict__ OUT) {
  int tid = threadIdx.x;
  int wave = tid >> 6, lane = tid & 63;
  int r = lane & 15, kg = lane >> 4;
  int i0 = blockIdx.x * 128 + wave * 32;
  int m0 = blockIdx.y * 64;
  const __hip_bfloat16* xh0 = Xh + (size_t)(i0 + r) * 768 + kg * 8;
  const __hip_bfloat16* xh1 = Xh + (size_t)(i0 + 16 + r) * 768 + kg * 8;
  const __hip_bfloat16* xl0 = Xl + (size_t)(i0 + r) * 768 + kg * 8;
  const __hip_bfloat16* xl1 = Xl + (size_t)(i0 + 16 + r) * 768 + kg * 8;
  const __hip_bfloat16* uh = Uh + (size_t)(m0 + r) * 768 + kg * 8;
  f32x4 acc[2][4];
#pragma unroll
  for (int a = 0; a < 2; ++a)
#pragma unroll
    for (int b = 0; b < 4; ++b) acc[a][b] = {0.f, 0.f, 0.f, 0.f};
  for (int k0 = 0; k0 < 768; k0 += 32) {
    bf16x8 ah0 = *(const bf16x8*)(xh0 + k0);
    bf16x8 ah1 = *(const bf16x8*)(xh1 + k0);
    bf16x8 al0 = *(const bf16x8*)(xl0 + k0);
    bf16x8 al1 = *(const bf16x8*)(xl1 + k0);
    bf16x8 bh[4];
#pragma unroll
    for (int p = 0; p < 4; ++p) bh[p] = *(const bf16x8*)(uh + p * 12288 + k0);
#pragma unroll
    for (int p = 0; p < 4; ++p) {
      acc[0][p] = __builtin_amdgcn_mfma_f32_16x16x32_bf16(ah0, bh[p], acc[0][p], 0, 0, 0);
      acc[1][p] = __builtin_amdgcn_mfma_f32_16x16x32_bf16(ah1, bh[p], acc[1][p], 0, 0, 0);
      acc[0][p] = __builtin_amdgcn_mfma_f32_16x16x32_bf16(al0, bh[p], acc[0][p], 0, 0, 0);
      acc[1][p] = __builtin_amdgcn_mfma_f32_16x16x32_bf16(al1, bh[p], acc[1][p], 0, 0, 0);
    }
  }
#pragma unroll
  for (int a = 0; a < 2; ++a)
#pragma unroll
    for (int p = 0; p < 4; ++p)
#pragma unroll
      for (int jj = 0; jj < 4; ++jj)
        OUT[(size_t)(i0 + a * 16 + kg * 4 + jj) * 3072 + m0 + p * 16 + r] =
            __float2bfloat16(acc[a][p][jj]);
}

// Whole scan in ONE kernel: 64 independent WGs (one per batch row), 768 threads.
// No cross-WG communication exists: the recurrence is row-local. Per step:
//   matvec: thread t computes cols {t+768j}: j=0 -> W_d·c (hi+lo state, 2-pass),
//           j=1..4 -> W_g·h (hi-only state). Results stay in registers — thread t's
//           cols are exactly its own pw element's mv/gh values.
//   pw: identical hyperbolic math, 1 elem/thread, block reductions over 12 waves.
// State: fp32 master in LDS + packed fp16 hi/lo for the dot2 matvec.
__global__ __launch_bounds__(768, 1) void k_scan_rows(
    const uint2* __restrict__ W4, const __hip_bfloat16* __restrict__ UG,
    const float* __restrict__ XN, const float* __restrict__ TS,
    const float* __restrict__ kptr, const float* __restrict__ h0,
    const float* __restrict__ c0, float* __restrict__ out) {
  __shared__ float sc32[768], sh32[768];
  __shared__ unsigned scHi[384], scLo[384], shHi[384];
  __shared__ float red[12 * 15];
  int r = blockIdx.x;
  int tid = threadIdx.x;
  float kk = kptr[0];
  float sq = sqrtf(-kk);

  sc32[tid] = c0[r * 768 + tid];
  sh32[tid] = h0[r * 768 + tid];
  __syncthreads();
  if (tid < 384) {
    float a = sc32[2 * tid], b = sc32[2 * tid + 1];
    unsigned hi = pk16(a, b);
    float hx, hy;
    unpk(hi, hx, hy);
    scHi[tid] = hi;
    scLo[tid] = pk16(a - hx, b - hy);
    shHi[tid] = pk16(sh32[2 * tid], sh32[2 * tid + 1]);
  }
  __syncthreads();

  size_t BSHc = (size_t)BB * SS * 768;

  for (int t = 0; t < SS; ++t) {
    int i = r * SS + t;
    const __hip_bfloat16* urow = UG + (size_t)i * 3072;
    float mx[4];
#pragma unroll
    for (int g = 0; g < 4; ++g) mx[g] = __bfloat162float(urow[g * 768 + tid]);
    float tv = TS[i];
    float uxn = XN[i];

    // ---- matvec: 5 cols/thread, dot2 over packed fp16 ----
    float a0 = 0.f, a0l = 0.f, a1 = 0.f, a2v = 0.f, a3v = 0.f, a4v = 0.f;
    {
      const uint2* wp = W4 + tid;
      const uint2* cH = (const uint2*)scHi;
      const uint2* cL = (const uint2*)scLo;
      const uint2* hH = (const uint2*)shHi;
#pragma unroll 4
      for (int k4 = 0; k4 < 192; ++k4) {
        uint2 c2 = cH[k4], l2 = cL[k4], hh = hH[k4];
        uint2 w0 = wp[(size_t)k4 * NCOL];
        uint2 w1 = wp[(size_t)k4 * NCOL + 768];
        uint2 w2 = wp[(size_t)k4 * NCOL + 1536];
        uint2 w3 = wp[(size_t)k4 * NCOL + 2304];
        uint2 w4v = wp[(size_t)k4 * NCOL + 3072];
        a0 = fdot2u(w0.x, c2.x, a0);
        a0 = fdot2u(w0.y, c2.y, a0);
        a0l = fdot2u(w0.x, l2.x, a0l);
        a0l = fdot2u(w0.y, l2.y, a0l);
        a1 = fdot2u(w1.x, hh.x, a1);
        a1 = fdot2u(w1.y, hh.y, a1);
        a2v = fdot2u(w2.x, hh.x, a2v);
        a2v = fdot2u(w2.y, hh.y, a2v);
        a3v = fdot2u(w3.x, hh.x, a3v);
        a3v = fdot2u(w3.y, hh.y, a3v);
        a4v = fdot2u(w4v.x, hh.x, a4v);
        a4v = fdot2u(w4v.y, hh.y, a4v);
      }
    }
    float mv = a0 + a0l;
    float gh[4] = {a1, a2v, a3v, a4v};
    float cc = sc32[tid];
    float h = sh32[tid];

    // ---- pw (scalar per thread) ----
    float sv[15];
    sv[0] = cc * cc;
    sv[1] = h * h;
    sv[2] = mv * mv;
#pragma unroll
    for (int g = 0; g < 4; ++g) {
      sv[3 + g] = gh[g] * gh[g];
      sv[7 + g] = gh[g] * mx[g];
      sv[11 + g] = mx[g] * mx[g];
    }
    redu12<15>(sv, red);
    float c2s = sv[0], h2s = sv[1], mvn2 = sv[2];
    float xn_c = fmaxf(sqrtf(c2s), MINN);
    float xn_h = fmaxf(sqrtf(h2s), MINN);
    float mxn_d = fmaxf(sqrtf(mvn2), MINN);

    float r_d = (mxn_d / xn_c) * artan_k_(xn_c, sq);
    float twd = tan_k_(r_d, sq);
    float wdsc = twd / mxn_d;
    float yn_d = fmaxf(fabsf(twd), MINN);
    float lsc = (artan_k_(yn_d, sq) / yn_d) * wdsc;
    float th = tanhf(lsc * mv);

    float ak_h = artan_k_(xn_h, sq);
    float ak_u = artan_k_(uxn, sq);
    float gate[4];
#pragma unroll
    for (int g = 0; g < 4; ++g) {
      float ghn = fmaxf(sqrtf(sv[3 + g]), MINN);
      float tg = tan_k_((ghn / xn_h) * ak_h, sq);
      float wsc = tg / ghn;
      float w2s = tg * tg;
      float umxn = fmaxf(sqrtf(sv[11 + g]), MINN);
      float us = tan_k_((umxn / uxn) * ak_u, sq) / umxn;
      float u2 = us * us * sv[11 + g];
      float xy = wsc * us * sv[7 + g];
      float den = fmaxf(1.f - 2.f * kk * xy + kk * kk * w2s * u2, MINN);
      float aa = (1.f - 2.f * kk * xy - kk * u2) / den;
      float bb = (1.f + kk * w2s) / den;
      float y2s = fmaxf(aa * aa * w2s + 2.f * aa * bb * xy + bb * bb * u2, 0.f);
      float yn = fmaxf(sqrtf(y2s), MINN);
      float psc = artan_k_(yn, sq) / yn;
      gate[g] = 1.f / (1.f + expf(-psc * (aa * wsc * gh[g] + bb * us * mx[g])));
    }

    float s2v[2] = {th * th, th * cc};
    redu12<2>(s2v, red);
    float un = fmaxf(sqrtf(s2v[0]), MINN);
    float esc = tan_k_(un, sq) / un;
    float cs1 = esc * th;
    float d1 = esc * s2v[1];
    float s1sq = esc * esc * s2v[0];

    float xnt = fmaxf(sqrtf(768.f * tv * tv), MINN);
    float wxn_t = fmaxf(fabsf(tv) * sqrtf(s1sq), MINN);
    float s2s = tan_k_((wxn_t / xnt) * artan_k_(xnt, sq), sq) / wxn_t * tv;
    float s2sq = s2s * s2s * s1sq;

    float den_l = fmaxf(1.f + 2.f * kk * d1 + kk * kk * s1sq * c2s, MINN);
    float al = (1.f + 2.f * kk * d1 - kk * c2s) / den_l;
    float bl = (1.f + kk * s1sq) / den_l;
    float pcl = -al, qcl = bl;

    float xy2 = s2s * (pcl * s1sq + qcl * d1);
    float x2b = fmaxf(pcl * pcl * s1sq + 2.f * pcl * qcl * d1 + qcl * qcl * c2s, 0.f);
    float y2b = s2sq;
    float den2 = fmaxf(1.f - 2.f * kk * xy2 + kk * kk * x2b * y2b, MINN);
    float a2c = (1.f - 2.f * kk * xy2 - kk * y2b) / den2;
    float b2c = (1.f + kk * x2b) / den2;
    float g1c = a2c * pcl + b2c * s2s;
    float g2c = a2c * qcl;
    float cadj = g1c * cs1 + g2c * cc;
    float adjsq = fmaxf(g1c * g1c * s1sq + 2.f * g1c * g2c * d1 + g2c * g2c * c2s, 0.f);

    float wxi = gate[1] * gate[3];
    float wxf = gate[0] * cadj;
    float s3v[4] = {gate[3] * gate[3], wxi * wxi, wxf * wxf, wxi * wxf};
    redu12<4>(s3v, red);
    float xnct = fmaxf(sqrtf(s3v[0]), MINN);
    float wxni = fmaxf(sqrtf(s3v[1]), MINN);
    float psi = tan_k_((wxni / xnct) * artan_k_(xnct, sq), sq) / wxni;
    float pi2 = psi * psi * s3v[1];
    float xnadj = fmaxf(sqrtf(adjsq), MINN);
    float wxnf = fmaxf(sqrtf(s3v[2]), MINN);
    float psf = tan_k_((wxnf / xnadj) * artan_k_(xnadj, sq), sq) / wxnf;
    float pf2 = psf * psf * s3v[2];
    float xyp = psi * psf * s3v[3];
    float den3 = fmaxf(1.f - 2.f * kk * xyp + kk * kk * pi2 * pf2, MINN);
    float a3c = (1.f - 2.f * kk * xyp - kk * pf2) / den3;
    float b3c = (1.f + kk * pi2) / den3;
    float nc = a3c * psi * wxi + b3c * psf * wxf;
    float tc = tanhf(nc);
    float gt = gate[2] * tc;
    float s4v[2] = {tc * tc, gt * gt};
    redu12<2>(s4v, red);
    float unh = fmaxf(sqrtf(s4v[0]), MINN);
    float ehs = tan_k_(unh, sq) / unh;
    float Esq = ehs * ehs * s4v[0];
    float En = fmaxf(sqrtf(Esq), MINN);
    float wxno = fmaxf(ehs * sqrtf(s4v[1]), MINN);
    float pso = tan_k_((wxno / En) * artan_k_(En, sq), sq) / wxno;

    out[((size_t)r * SS + t) * 768 + tid] = gate[2];  // output = o gate
    float nh = pso * (gate[2] * (ehs * tc));
    sc32[tid] = nc;
    sh32[tid] = nh;
    if (t == SS - 1) {
      out[BSHc + (size_t)r * 768 + tid] = nh;                    // h_last
      out[BSHc + (size_t)BB * 768 + (size_t)r * 768 + tid] = nc; // c_last
    }
    __syncthreads();
    if (t < SS - 1 && tid < 384) {
      float a = sc32[2 * tid], b = sc32[2 * tid + 1];
      unsigned hi = pk16(a, b);
      float hx, hy;
      unpk(hi, hx, hy);
      scHi[tid] = hi;
      scLo[tid] = pk16(a - hx, b - hy);
      shHi[tid] = pk16(sh32[2 * tid], sh32[2 * tid + 1]);
    }
    __syncthreads();
  }
}

extern "C" void kernel_launch(void* const* d_in, const int* in_sizes, int n_in,
                              void* d_out, int out_size, void* d_ws, size_t ws_size,
                              hipStream_t stream) {
  const float* inputs = (const float*)d_in[0];
  const float* ts = (const float*)d_in[1];
  const float* h0 = (const float*)d_in[2];
  const float* c0 = (const float*)d_in[3];
  const float* W_all = (const float*)d_in[4];
  const float* U_all = (const float*)d_in[5];
  const float* W_d = (const float*)d_in[6];
  const float* kptr = (const float*)d_in[7];
  float* ws = (float*)d_ws;
  float* out = (float*)d_out;

  // all offsets in float units
  size_t oW4 = 0;                       // fp16 weights: 2,949,120 half = 1,474,560 fl
  size_t oXN = oW4 + 1474560;           // 8192
  size_t oUG = oXN + 8192;              // 12,582,912
  size_t oXH = oUG + 12582912;          // 3,145,728
  size_t oXL = oXH + 3145728;           // 3,145,728
  size_t oUH = oXL + 3145728;           // 1,179,648
  size_t oUL = oUH + 1179648;           // 1,179,648 (lo written by split, unused)

  uint2* w4 = (uint2*)(ws + oW4);
  float* xn = ws + oXN;
  __hip_bfloat16* ug = (__hip_bfloat16*)(ws + oUG);
  __hip_bfloat16* xhh = (__hip_bfloat16*)(ws + oXH);
  __hip_bfloat16* xll = (__hip_bfloat16*)(ws + oXL);
  __hip_bfloat16* uhh = (__hip_bfloat16*)(ws + oUH);
  __hip_bfloat16* ull = (__hip_bfloat16*)(ws + oUL);

  k_build_w4<<<192, 256, 0, stream>>>(W_all, W_d, w4);
  k_split<<<(6291456 / 4 + 255) / 256, 256, 0, stream>>>(inputs, xhh, xll, 6291456 / 4);
  k_split<<<(2359296 / 4 + 255) / 256, 256, 0, stream>>>(U_all, uhh, ull, 2359296 / 4);
  k_gemm_xu_mfma<<<dim3(64, 48), 256, 0, stream>>>(xhh, xll, uhh, ug);
  k_xnorm<<<BB * SS, 256, 0, stream>>>(inputs, xn);
  k_scan_rows<<<BB, 768, 0, stream>>>(w4, ug, xn, ts, kptr, h0, c0, out);
}